// Round 8
// baseline (936.791 us; speedup 1.0000x reference)
//
#include <hip/hip_runtime.h>
#include <hip/hip_bf16.h>
#include <stdint.h>

// ---------------------------------------------------------------------------
// AdaptiveAngleConv: 5 angles of (bilinear deform-sample -> 3x3 conv)
// x: (2,256,64,64) f32, weight: (256,256,3,3) f32
// out: 5 x (2,256,190,190) f32 concatenated
//
// Conv = window implicit GEMM, operand-read-minimized:
//  - whole 4row x 68col x 256ic xo window staged to LDS ONCE per block
//    (139 KB, 3 barriers/block total)
//  - 9 taps = shifted views of the window (no A re-staging per tap)
//  - B (weights) in VGPRs, double-buffered by (tap,ks4) group, prefetched
//    one group ahead (statically indexed, rule-20 safe)
//  - wave tile 64px x 64oc -> each A ds_read_b128 feeds 2 MFMAs
//  - XOR-32 slot swizzle on A (involution on stage-src and read)
// ---------------------------------------------------------------------------

#define S2F 1.41421356237309515f

__constant__ float c_ox[5][9] = {
  {0.f,0.f,0.f,0.f,0.f,0.f,0.f,0.f,0.f},
  {1.f-S2F, 1.f-S2F*0.5f, 1.f, -S2F*0.5f, 0.f, S2F*0.5f, -1.f, S2F*0.5f-1.f, S2F-1.f},
  {0.f,1.f,2.f,-1.f,0.f,1.f,-2.f,-1.f,0.f},
  {1.f, 1.f+S2F*0.5f, 1.f+S2F, -S2F*0.5f, 0.f, S2F*0.5f, -1.f-S2F, -1.f-S2F*0.5f, -1.f},
  {2.f,2.f,2.f,0.f,0.f,0.f,-2.f,-2.f,-2.f}
};
__constant__ float c_oy[5][9] = {
  {0.f,0.f,0.f,0.f,0.f,0.f,0.f,0.f,0.f},
  {1.f, S2F*0.5f, S2F-1.f, 1.f-S2F*0.5f, 0.f, S2F*0.5f-1.f, 1.f-S2F, -S2F*0.5f, -1.f},
  {2.f,1.f,0.f,1.f,0.f,-1.f,0.f,-1.f,-2.f},
  {1.f+S2F, S2F*0.5f, -1.f, 1.f+S2F*0.5f, 0.f, -1.f-S2F*0.5f, 1.f, -S2F*0.5f, 1.f+S2F},
  {2.f,0.f,-2.f,2.f,0.f,-2.f,2.f,0.f,-2.f}
};

typedef __bf16 bf16x8_t __attribute__((ext_vector_type(8)));
typedef float f32x4_t __attribute__((ext_vector_type(4)));
typedef float f32x16_t __attribute__((ext_vector_type(16)));

typedef const __attribute__((address_space(1))) void* as1cp;
typedef __attribute__((address_space(3))) void* as3p;

__device__ __forceinline__ void gload16(const void* g, void* l) {
  __builtin_amdgcn_global_load_lds((as1cp)g, (as3p)l, 16, 0, 0);
}

// x NCHW (2,256,64,64) -> xT NHWC (2,64,64,256) f32
__global__ void k_transpose(const float* __restrict__ x, float* __restrict__ xT) {
  const int v = blockIdx.x, u = blockIdx.y, b = blockIdx.z;
  const int ic = threadIdx.x;
  xT[(((b*64 + u)*64 + v)*256) + ic] =
      x[(((b*256 + ic)*64 + u)*64) + v];
}

// weight OIHW (256,256,3,3) f32 -> wb2 packed bf16:
// wb2[tap][ks16][hi][oc 256][e 8], entry = W[oc][ks16*16+hi*8+e][tap]
__global__ void k_wconv(const float* __restrict__ w, __hip_bfloat16* __restrict__ wb2) {
  const int g = blockIdx.x*256 + threadIdx.x;   // < 9*16*2*256*8 = 589824
  const int e  = g & 7;
  const int oc = (g >> 3) & 255;
  const int r  = g >> 11;                       // 0..287
  const int hi   = r & 1;
  const int ks16 = (r >> 1) & 15;
  const int tap  = r >> 5;                      // 0..8
  const int ic = ks16*16 + hi*8 + e;
  wb2[g] = __float2bfloat16(w[(oc*256 + ic)*9 + tap]);
}

// bilinear deform-sample -> xo bf16 NHWC [(a)][b][192][192][256]
__global__ void k_sample(const float* __restrict__ xT,
                         __hip_bfloat16* __restrict__ xo, int a0)
{
  const int aidx = a0 + blockIdx.z;
  __hip_bfloat16* xoa = xo + (size_t)blockIdx.z * (2ull*192*192*256);

  const int tid = threadIdx.x;           // 256
  const int ic = (tid & 63) * 4;
  const int j = blockIdx.x*4 + (tid >> 6);
  const int i = blockIdx.y;

  const int a = i / 3, r = i - 3*a;
  const int bc = j / 3, s = j - 3*bc;
  const int n = r*3 + s;
  const float px = (float)(a + r) + c_ox[aidx][n];
  const float py = (float)(bc + s) + c_oy[aidx][n];
  const float fx = floorf(px), fy = floorf(py);
  const float pxc = fminf(fmaxf(px, 0.f), 65.f);
  const float pyc = fminf(fmaxf(py, 0.f), 65.f);
  const int qlx = (int)fminf(fmaxf(fx,      0.f), 65.f);
  const int qrx = (int)fminf(fmaxf(fx + 1.f, 0.f), 65.f);
  const int qly = (int)fminf(fmaxf(fy,      0.f), 65.f);
  const int qry = (int)fminf(fmaxf(fy + 1.f, 0.f), 65.f);
  const float wlx = 1.f + (float)qlx - pxc;
  const float wrx = 1.f - (float)qrx + pxc;
  const float wly = 1.f + (float)qly - pyc;
  const float wry = 1.f - (float)qry + pyc;
  const float glt = wlx*wly, grb = wrx*wry, glb = wlx*wry, grt = wrx*wly;

  const bool inxl = (qlx >= 1) && (qlx <= 64);
  const bool inxr = (qrx >= 1) && (qrx <= 64);
  const bool inyl = (qly >= 1) && (qly <= 64);
  const bool inyr = (qry >= 1) && (qry <= 64);

  const f32x4_t zero = (f32x4_t){0.f,0.f,0.f,0.f};
  #pragma unroll
  for (int b = 0; b < 2; ++b) {
    const float* xb = xT + (size_t)b * (64*64*256);
    f32x4_t vlt = (inxl && inyl) ? *(const f32x4_t*)&xb[((qlx-1)*64 + (qly-1))*256 + ic] : zero;
    f32x4_t vrb = (inxr && inyr) ? *(const f32x4_t*)&xb[((qrx-1)*64 + (qry-1))*256 + ic] : zero;
    f32x4_t vlb = (inxl && inyr) ? *(const f32x4_t*)&xb[((qlx-1)*64 + (qry-1))*256 + ic] : zero;
    f32x4_t vrt = (inxr && inyl) ? *(const f32x4_t*)&xb[((qrx-1)*64 + (qly-1))*256 + ic] : zero;
    ushort4 pk;
    float v0 = glt*vlt[0] + grb*vrb[0] + glb*vlb[0] + grt*vrt[0];
    float v1 = glt*vlt[1] + grb*vrb[1] + glb*vlb[1] + grt*vrt[1];
    float v2 = glt*vlt[2] + grb*vrb[2] + glb*vlb[2] + grt*vrt[2];
    float v3 = glt*vlt[3] + grb*vrb[3] + glb*vlb[3] + grt*vrt[3];
    pk.x = __hip_bfloat16_raw(__float2bfloat16(v0)).x;
    pk.y = __hip_bfloat16_raw(__float2bfloat16(v1)).x;
    pk.z = __hip_bfloat16_raw(__float2bfloat16(v2)).x;
    pk.w = __hip_bfloat16_raw(__float2bfloat16(v3)).x;
    *(ushort4*)&xoa[(((size_t)b*192 + i)*192 + j)*256 + ic] = pk;
  }
}

// ---------------------------------------------------------------------------
// conv: window implicit GEMM. grid.x = nab*285 (bijective XCD chunking).
// Block: 128 px (2 out rows x 64 cols) x 256 oc; 512 thr / 8 waves (2Mx4N);
// wave tile 64px x 64oc = 2x2 frags of mfma_f32_32x32x16_bf16 (acc 64 VGPR).
// LDS window: [4 rows][68 cols][32 slots][16B] = 139264 B (slot ^= col&31).
// K loop: 36 groups (9 taps x 4 ks4-groups), B reg-dbuf, ZERO barriers inside.
// ---------------------------------------------------------------------------
__global__ __launch_bounds__(512, 1) void k_conv7(
    const __hip_bfloat16* __restrict__ xo,   // [ab][192][192][256] bf16
    const __hip_bfloat16* __restrict__ wb2,  // packed (see k_wconv)
    float* __restrict__ out)                 // + ab*9241600 : [256][190][190]
{
  extern __shared__ __align__(16) char smem[];

  const int nblk = gridDim.x;
  const int id = blockIdx.x;
  const int qq = nblk >> 3, rr = nblk & 7;
  const int xcd = id & 7, pos = id >> 3;
  const int swz = (xcd < rr ? xcd*(qq+1) : rr*(qq+1) + (xcd-rr)*qq) + pos;
  const int ab = swz / 285;
  const int rem = swz - ab*285;
  const int it = rem / 3;                    // 0..94
  const int jt = rem - it*3;                 // 0..2
  const int i0 = it*2, j0 = jt*64;

  const int tid = threadIdx.x;
  const int w = tid >> 6, l = tid & 63;
  const int l31 = l & 31, hi = l >> 5;
  const int wm = w >> 2, wn = w & 3;         // 2M x 4N

  const char* xob = (const char*)(xo + (size_t)ab * 9437184u);
  const char* wbc = (const char*)wb2;

  // --- stage whole window: 17 chunks/thread, chunk c = tid + t*512 ---
  // window [r 4][p 68][s 32][16B]; LDS holds global ic-slot (s ^ (p&31))
  int sOff[17];
  #pragma unroll
  for (int t = 0; t < 17; ++t) {
    const int c = tid + t*512;
    const int r = c / 2176;
    const int c2 = c - r*2176;
    const int p = c2 >> 5, s = c2 & 31;
    int j = j0 + p; if (j > 191) j = 191;    // pad cols (never feed stored out)
    sOff[t] = ((i0 + r)*192 + j)*512 + ((s ^ (p & 31)) << 4);
  }
  #pragma unroll
  for (int t = 0; t < 17; ++t)
    gload16(xob + (size_t)(unsigned)sOff[t], smem + tid*16 + t*8192);

  // --- B register double-buffer: group g (0..35) = tap*4 + kg ---
  const int bB = hi*4096 + (wn*64 + l31)*16;
  bf16x8_t B0[8], B1[8];
  auto loadB = [&](bf16x8_t (&B)[8], int g) {
    const char* base = wbc + (size_t)((g >> 2)*16 + (g & 3)*4) * 8192 + bB;
    #pragma unroll
    for (int q = 0; q < 4; ++q) {
      B[q*2 + 0] = *(const bf16x8_t*)(base + q*8192);
      B[q*2 + 1] = *(const bf16x8_t*)(base + q*8192 + 512);
    }
  };

  f32x16_t a00, a01, a10, a11;
  #pragma unroll
  for (int v = 0; v < 16; ++v) { a00[v] = 0.f; a01[v] = 0.f; a10[v] = 0.f; a11[v] = 0.f; }

  auto compute = [&](int g, bf16x8_t (&B)[8]) {
    const int tap = g >> 2, kg = g & 3;
    const int ki = (tap >= 6) ? 2 : ((tap >= 3) ? 1 : 0);
    const int kj = tap - ki*3;
    const char* Ab = smem + (wm + ki)*34816 + (l31 + kj)*512;
    const int swzc = (l31 + kj) & 31;
    #pragma unroll
    for (int q = 0; q < 4; ++q) {
      const int t0 = (kg*4 + q)*2 + hi;
      const int so = ((t0 ^ swzc) << 4);
      const bf16x8_t af0 = *(const bf16x8_t*)(Ab + so);           // mf=0 cols
      const bf16x8_t af1 = *(const bf16x8_t*)(Ab + 16384 + so);   // mf=1 cols
      a00 = __builtin_amdgcn_mfma_f32_32x32x16_bf16(af0, B[q*2+0], a00, 0, 0, 0);
      a01 = __builtin_amdgcn_mfma_f32_32x32x16_bf16(af0, B[q*2+1], a01, 0, 0, 0);
      a10 = __builtin_amdgcn_mfma_f32_32x32x16_bf16(af1, B[q*2+0], a10, 0, 0, 0);
      a11 = __builtin_amdgcn_mfma_f32_32x32x16_bf16(af1, B[q*2+1], a11, 0, 0, 0);
    }
  };

  loadB(B0, 0);
  __syncthreads();                           // window + B0 ready

  for (int gg = 0; gg < 36; gg += 2) {
    loadB(B1, gg + 1);
    compute(gg, B0);
    if (gg + 2 < 36) loadB(B0, gg + 2);
    compute(gg + 1, B1);
  }

  // --- epilogue: eps f32[256 oc][132 px] = 135168 B (reuse window LDS) ---
  __syncthreads();
  float* eps = (float*)smem;
  {
    const int row0 = (wn*64 + l31);          // oc for nf=0
    const int colb = wm*64;                  // px base
    #pragma unroll
    for (int qv = 0; qv < 4; ++qv) {
      const int pxo = qv*8 + 4*hi;
      *(f32x4_t*)&eps[(row0     )*132 + colb      + pxo] = (f32x4_t){a00[qv*4+0], a00[qv*4+1], a00[qv*4+2], a00[qv*4+3]};
      *(f32x4_t*)&eps[(row0 + 32)*132 + colb      + pxo] = (f32x4_t){a01[qv*4+0], a01[qv*4+1], a01[qv*4+2], a01[qv*4+3]};
      *(f32x4_t*)&eps[(row0     )*132 + colb + 32 + pxo] = (f32x4_t){a10[qv*4+0], a10[qv*4+1], a10[qv*4+2], a10[qv*4+3]};
      *(f32x4_t*)&eps[(row0 + 32)*132 + colb + 32 + pxo] = (f32x4_t){a11[qv*4+0], a11[qv*4+1], a11[qv*4+2], a11[qv*4+3]};
    }
  }
  __syncthreads();

  float* outab = out + (size_t)ab * 9241600u;
  const int ocr = tid >> 1, half = tid & 1;
  const int iS = i0 + half;                  // <= 189 always
  const int kmax = (jt == 2) ? 62 : 64;
  float* dst = outab + (size_t)ocr*36100u + iS*190 + j0;
  const float* src = eps + ocr*132 + half*64;
  for (int k = 0; k < kmax; k += 2)
    *(float2*)(dst + k) = make_float2(src[k], src[k + 1]);
}

extern "C" void kernel_launch(void* const* d_in, const int* in_sizes, int n_in,
                              void* d_out, int out_size, void* d_ws, size_t ws_size,
                              hipStream_t stream)
{
  const float* x = (const float*)d_in[0];
  const float* w = (const float*)d_in[1];
  float* out = (float*)d_out;

  char* ws = (char*)d_ws;
  float*          xT  = (float*)ws;                        // 8,388,608 B
  __hip_bfloat16* wb2 = (__hip_bfloat16*)(ws + 8388608);   // 1,179,648 B
  __hip_bfloat16* xo  = (__hip_bfloat16*)(ws + 9568256);   // 5 or 1 x 37,748,736 B

  const bool merged = (ws_size >= 198311936ull);

  (void)hipFuncSetAttribute((const void*)k_conv7,
                            hipFuncAttributeMaxDynamicSharedMemorySize, 139264);

  k_transpose<<<dim3(64, 64, 2), 256, 0, stream>>>(x, xT);
  k_wconv<<<2304, 256, 0, stream>>>(w, wb2);

  if (merged) {
    k_sample<<<dim3(48, 192, 5), 256, 0, stream>>>(xT, xo, 0);
    k_conv7<<<2850, 512, 139264, stream>>>(xo, wb2, out);
  } else {
    for (int aidx = 0; aidx < 5; ++aidx) {
      k_sample<<<dim3(48, 192, 1), 256, 0, stream>>>(xT, xo, aidx);
      k_conv7<<<570, 512, 139264, stream>>>(xo, wb2, out + (size_t)aidx * 18483200u);
    }
  }
}

// Round 9
// 575.570 us; speedup vs baseline: 1.6276x; 1.6276x over previous
//
#include <hip/hip_runtime.h>
#include <hip/hip_bf16.h>
#include <stdint.h>

// ---------------------------------------------------------------------------
// AdaptiveAngleConv: 5 angles of (bilinear deform-sample -> 3x3 conv)
// x: (2,256,64,64) f32, weight: (256,256,3,3) f32
// out: 5 x (2,256,190,190) f32 concatenated
// Conv = round-1 structure (m97-style): 128x128 tile, BK=64, 32 MFMA
// (16x16x32) + 16 ds_read_b128 per step, plain __syncthreads dbuf loop,
// 66KB static LDS -> 2 blocks/CU. MERGED: one 5700-block dispatch
// (blockIdx.z = angle*2 + batch; out offset = z*9241600 floats).
// ---------------------------------------------------------------------------

#define S2F 1.41421356237309515f

__constant__ float c_ox[5][9] = {
  {0.f,0.f,0.f,0.f,0.f,0.f,0.f,0.f,0.f},
  {1.f-S2F, 1.f-S2F*0.5f, 1.f, -S2F*0.5f, 0.f, S2F*0.5f, -1.f, S2F*0.5f-1.f, S2F-1.f},
  {0.f,1.f,2.f,-1.f,0.f,1.f,-2.f,-1.f,0.f},
  {1.f, 1.f+S2F*0.5f, 1.f+S2F, -S2F*0.5f, 0.f, S2F*0.5f, -1.f-S2F, -1.f-S2F*0.5f, -1.f},
  {2.f,2.f,2.f,0.f,0.f,0.f,-2.f,-2.f,-2.f}
};
__constant__ float c_oy[5][9] = {
  {0.f,0.f,0.f,0.f,0.f,0.f,0.f,0.f,0.f},
  {1.f, S2F*0.5f, S2F-1.f, 1.f-S2F*0.5f, 0.f, S2F*0.5f-1.f, 1.f-S2F, -S2F*0.5f, -1.f},
  {2.f,1.f,0.f,1.f,0.f,-1.f,0.f,-1.f,-2.f},
  {1.f+S2F, S2F*0.5f, -1.f, 1.f+S2F*0.5f, 0.f, -1.f-S2F*0.5f, 1.f, -S2F*0.5f, 1.f+S2F},
  {2.f,0.f,-2.f,2.f,0.f,-2.f,2.f,0.f,-2.f}
};

typedef __bf16 bf16x8_t __attribute__((ext_vector_type(8)));
typedef float f32x4_t __attribute__((ext_vector_type(4)));

typedef const __attribute__((address_space(1))) void* as1cp;
typedef __attribute__((address_space(3))) void* as3p;

__device__ __forceinline__ void gload16(const void* g, void* l) {
  __builtin_amdgcn_global_load_lds((as1cp)g, (as3p)l, 16, 0, 0);
}

// x NCHW (2,256,64,64) -> xT NHWC (2,64,64,256) f32
__global__ void k_transpose(const float* __restrict__ x, float* __restrict__ xT) {
  const int v = blockIdx.x, u = blockIdx.y, b = blockIdx.z;
  const int ic = threadIdx.x;
  xT[(((b*64 + u)*64 + v)*256) + ic] =
      x[(((b*256 + ic)*64 + u)*64) + v];
}

// weight OIHW (256,256,3,3) f32 -> wb (9,256,256)=[t][oc][ic] bf16
__global__ void k_wconv(const float* __restrict__ w, __hip_bfloat16* __restrict__ wb) {
  const int tid = blockIdx.x*256 + threadIdx.x;   // < 9*256*256
  const int t = tid >> 16;
  const int rem = tid & 65535;
  const int oc = rem >> 8;
  const int ic = rem & 255;
  wb[tid] = __float2bfloat16(w[(oc*256 + ic)*9 + t]);
}

// bilinear deform-sample -> xo bf16 NHWC [(a)][b][192][192][256]
// grid (48, 192, nA): blockIdx.z selects angle (a0 + z); 4 ic per thread.
__global__ void k_sample(const float* __restrict__ xT,
                         __hip_bfloat16* __restrict__ xo, int a0)
{
  const int aidx = a0 + blockIdx.z;
  __hip_bfloat16* xoa = xo + (size_t)blockIdx.z * (2ull*192*192*256);

  const int tid = threadIdx.x;           // 256
  const int ic = (tid & 63) * 4;
  const int j = blockIdx.x*4 + (tid >> 6);
  const int i = blockIdx.y;

  const int a = i / 3, r = i - 3*a;
  const int bc = j / 3, s = j - 3*bc;
  const int n = r*3 + s;
  const float px = (float)(a + r) + c_ox[aidx][n];
  const float py = (float)(bc + s) + c_oy[aidx][n];
  const float fx = floorf(px), fy = floorf(py);
  const float pxc = fminf(fmaxf(px, 0.f), 65.f);
  const float pyc = fminf(fmaxf(py, 0.f), 65.f);
  const int qlx = (int)fminf(fmaxf(fx,      0.f), 65.f);
  const int qrx = (int)fminf(fmaxf(fx + 1.f, 0.f), 65.f);
  const int qly = (int)fminf(fmaxf(fy,      0.f), 65.f);
  const int qry = (int)fminf(fmaxf(fy + 1.f, 0.f), 65.f);
  const float wlx = 1.f + (float)qlx - pxc;
  const float wrx = 1.f - (float)qrx + pxc;
  const float wly = 1.f + (float)qly - pyc;
  const float wry = 1.f - (float)qry + pyc;
  const float glt = wlx*wly, grb = wrx*wry, glb = wlx*wry, grt = wrx*wly;

  const bool inxl = (qlx >= 1) && (qlx <= 64);
  const bool inxr = (qrx >= 1) && (qrx <= 64);
  const bool inyl = (qly >= 1) && (qly <= 64);
  const bool inyr = (qry >= 1) && (qry <= 64);

  const f32x4_t zero = (f32x4_t){0.f,0.f,0.f,0.f};
  #pragma unroll
  for (int b = 0; b < 2; ++b) {
    const float* xb = xT + (size_t)b * (64*64*256);
    f32x4_t vlt = (inxl && inyl) ? *(const f32x4_t*)&xb[((qlx-1)*64 + (qly-1))*256 + ic] : zero;
    f32x4_t vrb = (inxr && inyr) ? *(const f32x4_t*)&xb[((qrx-1)*64 + (qry-1))*256 + ic] : zero;
    f32x4_t vlb = (inxl && inyr) ? *(const f32x4_t*)&xb[((qlx-1)*64 + (qry-1))*256 + ic] : zero;
    f32x4_t vrt = (inxr && inyl) ? *(const f32x4_t*)&xb[((qrx-1)*64 + (qly-1))*256 + ic] : zero;
    ushort4 pk;
    float v0 = glt*vlt[0] + grb*vrb[0] + glb*vlb[0] + grt*vrt[0];
    float v1 = glt*vlt[1] + grb*vrb[1] + glb*vlb[1] + grt*vrt[1];
    float v2 = glt*vlt[2] + grb*vrb[2] + glb*vlb[2] + grt*vrt[2];
    float v3 = glt*vlt[3] + grb*vrb[3] + glb*vlb[3] + grt*vrt[3];
    pk.x = __hip_bfloat16_raw(__float2bfloat16(v0)).x;
    pk.y = __hip_bfloat16_raw(__float2bfloat16(v1)).x;
    pk.z = __hip_bfloat16_raw(__float2bfloat16(v2)).x;
    pk.w = __hip_bfloat16_raw(__float2bfloat16(v3)).x;
    *(ushort4*)&xoa[(((size_t)b*192 + i)*192 + j)*256 + ic] = pk;
  }
}

// implicit-GEMM conv: M=128 px (2 rows x 64 cols), N=128 oc, K=9 taps x 256 ic
// grid (6, 95, nZ): x = ntile(2) x coltile(3), y = row-pair, z = ab index
// (merged: z = angle*2 + batch; per-angle fallback: z = batch)
__global__ __launch_bounds__(256, 2) void k_conv(
    const __hip_bfloat16* __restrict__ xo,   // [z][192][192][256] bf16
    const __hip_bfloat16* __restrict__ wb,   // [9][256][256] bf16 (t,oc,ic)
    float* __restrict__ out)                 // + z*9241600 : [256][190][190]
{
  __shared__ __align__(16) char smem[66048];
  const int tid = threadIdx.x;
  const int nt = blockIdx.x & 1;
  const int ct = blockIdx.x >> 1;
  const int i0 = blockIdx.y * 2;
  const int z  = blockIdx.z;
  const int oc0 = nt * 128;
  const int j0 = ct * 64;

  const int q8   = tid >> 3;           // 0..31
  const int slot = tid & 7;
  const int wv   = tid >> 6;           // wave 0..3
  const int sw   = slot ^ (q8 & 7);    // XOR-swizzled 16B slot (pre-swizzle source)

  const char* xob = (const char*)xo + (size_t)z * 18874368u;
  const char* wbc = (const char*)wb;

  int arow[4], acol[4], brow[4];
  #pragma unroll
  for (int p = 0; p < 4; ++p) {
    const int m = p*32 + q8;
    arow[p] = i0 + (m >> 6);
    acol[p] = j0 + (m & 63);
    brow[p] = oc0 + m;
  }

  f32x4_t acc[4][4];
  #pragma unroll
  for (int fm = 0; fm < 4; ++fm)
    #pragma unroll
    for (int fn = 0; fn < 4; ++fn)
      acc[fm][fn] = (f32x4_t){0.f, 0.f, 0.f, 0.f};

  const int lane = tid & 63;
  const int lrow = lane & 15;
  const int lk   = lane >> 4;
  const int wm   = wv >> 1;
  const int wn   = wv & 1;

  auto stage = [&](int kk, int cur) {
    const int t = kk >> 2, icg = kk & 3;
    const int ki = t / 3, kj = t - 3*ki;
    char* sa = smem + cur*16384 + wv*1024;
    char* sb = smem + 32768 + cur*16384 + wv*1024;
    #pragma unroll
    for (int p = 0; p < 4; ++p) {
      int col = acol[p] + kj; col = (col > 191) ? 191 : col;   // garbage cols clamped (never stored)
      const char* ga = xob + (((arow[p] + ki)*192 + col)*256 + icg*64)*2 + sw*16;
      gload16(ga, sa + p*4096);
      const char* gb = wbc + ((t*256 + brow[p])*256 + icg*64)*2 + sw*16;
      gload16(gb, sb + p*4096);
    }
  };

  auto compute = [&](int cur) {
    const char* sa = smem + cur*16384;
    const char* sb = smem + 32768 + cur*16384;
    bf16x8_t af[4][2], bfr[4][2];
    #pragma unroll
    for (int f = 0; f < 4; ++f) {
      const int m = wm*64 + f*16 + lrow;
      const int n = wn*64 + f*16 + lrow;
      #pragma unroll
      for (int ks = 0; ks < 2; ++ks) {
        af[f][ks]  = *(const bf16x8_t*)(sa + m*128 + (((ks*4 + lk) ^ (m & 7)) * 16));
        bfr[f][ks] = *(const bf16x8_t*)(sb + n*128 + (((ks*4 + lk) ^ (n & 7)) * 16));
      }
    }
    #pragma unroll
    for (int fm = 0; fm < 4; ++fm)
      #pragma unroll
      for (int fn = 0; fn < 4; ++fn)
        #pragma unroll
        for (int ks = 0; ks < 2; ++ks)
          acc[fm][fn] = __builtin_amdgcn_mfma_f32_16x16x32_bf16(
              af[fm][ks], bfr[fn][ks], acc[fm][fn], 0, 0, 0);
  };

  stage(0, 0);
  __syncthreads();
  for (int kk = 0; kk < 36; ++kk) {
    const int cur = kk & 1;
    if (kk < 35) stage(kk + 1, cur ^ 1);
    compute(cur);
    __syncthreads();
  }

  // epilogue: LDS transpose to [oc'][m'] (pad 129) for coalesced NCHW stores
  float* eps = (float*)smem;
  #pragma unroll
  for (int fm = 0; fm < 4; ++fm)
    #pragma unroll
    for (int fn = 0; fn < 4; ++fn)
      #pragma unroll
      for (int r = 0; r < 4; ++r)
        eps[(wn*64 + fn*16 + lrow)*129 + (wm*64 + fm*16 + lk*4 + r)] = acc[fm][fn][r];
  __syncthreads();

  float* outb = out + (size_t)z * 9241600u;
  #pragma unroll
  for (int pass = 0; pass < 16; ++pass) {
    const int ocw = pass*8 + (tid >> 5);
    const int m4  = (tid & 31) * 4;
    const int di  = m4 >> 6, jc = m4 & 63;
    const int i = i0 + di, j = j0 + jc;
    const float v0 = eps[ocw*129 + m4 + 0];
    const float v1 = eps[ocw*129 + m4 + 1];
    const float v2 = eps[ocw*129 + m4 + 2];
    const float v3 = eps[ocw*129 + m4 + 3];
    float* dst = outb + ((size_t)(oc0 + ocw)*190 + i)*190 + j;
    if (j + 3 < 190) {
      *(float2*)dst       = make_float2(v0, v1);   // 8B-aligned always
      *(float2*)(dst + 2) = make_float2(v2, v3);
    } else {
      if (j     < 190) dst[0] = v0;
      if (j + 1 < 190) dst[1] = v1;
      if (j + 2 < 190) dst[2] = v2;
      if (j + 3 < 190) dst[3] = v3;
    }
  }
}

extern "C" void kernel_launch(void* const* d_in, const int* in_sizes, int n_in,
                              void* d_out, int out_size, void* d_ws, size_t ws_size,
                              hipStream_t stream)
{
  const float* x = (const float*)d_in[0];
  const float* w = (const float*)d_in[1];
  float* out = (float*)d_out;

  char* ws = (char*)d_ws;
  float*          xT = (float*)ws;                         // 8,388,608 B
  __hip_bfloat16* wb = (__hip_bfloat16*)(ws + 8388608);    // 1,179,648 B
  __hip_bfloat16* xo = (__hip_bfloat16*)(ws + 9568256);    // 5 or 1 x 37,748,736 B

  const bool merged = (ws_size >= 198311936ull);

  k_transpose<<<dim3(64, 64, 2), 256, 0, stream>>>(x, xT);
  k_wconv<<<2304, 256, 0, stream>>>(w, wb);

  if (merged) {
    k_sample<<<dim3(48, 192, 5), 256, 0, stream>>>(xT, xo, 0);
    k_conv<<<dim3(6, 95, 10), 256, 0, stream>>>(xo, wb, out);
  } else {
    for (int aidx = 0; aidx < 5; ++aidx) {
      k_sample<<<dim3(48, 192, 1), 256, 0, stream>>>(xT, xo, aidx);
      k_conv<<<dim3(6, 95, 2), 256, 0, stream>>>(xo, wb, out + (size_t)aidx * 18483200u);
    }
  }
}

// Round 10
// 542.972 us; speedup vs baseline: 1.7253x; 1.0600x over previous
//
#include <hip/hip_runtime.h>
#include <hip/hip_bf16.h>
#include <stdint.h>

// ---------------------------------------------------------------------------
// AdaptiveAngleConv: 5 angles of (bilinear deform-sample -> 3x3 conv)
// x: (2,256,64,64) f32, weight: (256,256,3,3) f32
// out: 5 x (2,256,190,190) f32 concatenated
// Conv = round-1 structure (m97-style): 128x128 tile, BK=64, 32 MFMA
// (16x16x32) + 16 ds_read_b128 per step, plain __syncthreads dbuf loop,
// 66KB static LDS -> 2 blocks/CU. Merged 5700-block dispatch (z = ab).
// K order TAP-INNER (kk -> tap = kk%9, icg = kk/9): tap re-reads of the
// same xo window land within 9 consecutive K-steps -> L2-resident
// (~2.2MB/XCD working set), cutting HBM re-fetch ~6x.
// ---------------------------------------------------------------------------

#define S2F 1.41421356237309515f

__constant__ float c_ox[5][9] = {
  {0.f,0.f,0.f,0.f,0.f,0.f,0.f,0.f,0.f},
  {1.f-S2F, 1.f-S2F*0.5f, 1.f, -S2F*0.5f, 0.f, S2F*0.5f, -1.f, S2F*0.5f-1.f, S2F-1.f},
  {0.f,1.f,2.f,-1.f,0.f,1.f,-2.f,-1.f,0.f},
  {1.f, 1.f+S2F*0.5f, 1.f+S2F, -S2F*0.5f, 0.f, S2F*0.5f, -1.f-S2F, -1.f-S2F*0.5f, -1.f},
  {2.f,2.f,2.f,0.f,0.f,0.f,-2.f,-2.f,-2.f}
};
__constant__ float c_oy[5][9] = {
  {0.f,0.f,0.f,0.f,0.f,0.f,0.f,0.f,0.f},
  {1.f, S2F*0.5f, S2F-1.f, 1.f-S2F*0.5f, 0.f, S2F*0.5f-1.f, 1.f-S2F, -S2F*0.5f, -1.f},
  {2.f,1.f,0.f,1.f,0.f,-1.f,0.f,-1.f,-2.f},
  {1.f+S2F, S2F*0.5f, -1.f, 1.f+S2F*0.5f, 0.f, -1.f-S2F*0.5f, 1.f, -S2F*0.5f, 1.f+S2F},
  {2.f,0.f,-2.f,2.f,0.f,-2.f,2.f,0.f,-2.f}
};

typedef __bf16 bf16x8_t __attribute__((ext_vector_type(8)));
typedef float f32x4_t __attribute__((ext_vector_type(4)));

typedef const __attribute__((address_space(1))) void* as1cp;
typedef __attribute__((address_space(3))) void* as3p;

__device__ __forceinline__ void gload16(const void* g, void* l) {
  __builtin_amdgcn_global_load_lds((as1cp)g, (as3p)l, 16, 0, 0);
}

// x NCHW (2,256,64,64) -> xT NHWC (2,64,64,256) f32
__global__ void k_transpose(const float* __restrict__ x, float* __restrict__ xT) {
  const int v = blockIdx.x, u = blockIdx.y, b = blockIdx.z;
  const int ic = threadIdx.x;
  xT[(((b*64 + u)*64 + v)*256) + ic] =
      x[(((b*256 + ic)*64 + u)*64) + v];
}

// weight OIHW (256,256,3,3) f32 -> wb (9,256,256)=[t][oc][ic] bf16
__global__ void k_wconv(const float* __restrict__ w, __hip_bfloat16* __restrict__ wb) {
  const int tid = blockIdx.x*256 + threadIdx.x;   // < 9*256*256
  const int t = tid >> 16;
  const int rem = tid & 65535;
  const int oc = rem >> 8;
  const int ic = rem & 255;
  wb[tid] = __float2bfloat16(w[(oc*256 + ic)*9 + t]);
}

// bilinear deform-sample -> xo bf16 NHWC [(a)][b][192][192][256]
// grid (48, 192, nA): blockIdx.z selects angle (a0 + z); 4 ic per thread.
__global__ void k_sample(const float* __restrict__ xT,
                         __hip_bfloat16* __restrict__ xo, int a0)
{
  const int aidx = a0 + blockIdx.z;
  __hip_bfloat16* xoa = xo + (size_t)blockIdx.z * (2ull*192*192*256);

  const int tid = threadIdx.x;           // 256
  const int ic = (tid & 63) * 4;
  const int j = blockIdx.x*4 + (tid >> 6);
  const int i = blockIdx.y;

  const int a = i / 3, r = i - 3*a;
  const int bc = j / 3, s = j - 3*bc;
  const int n = r*3 + s;
  const float px = (float)(a + r) + c_ox[aidx][n];
  const float py = (float)(bc + s) + c_oy[aidx][n];
  const float fx = floorf(px), fy = floorf(py);
  const float pxc = fminf(fmaxf(px, 0.f), 65.f);
  const float pyc = fminf(fmaxf(py, 0.f), 65.f);
  const int qlx = (int)fminf(fmaxf(fx,      0.f), 65.f);
  const int qrx = (int)fminf(fmaxf(fx + 1.f, 0.f), 65.f);
  const int qly = (int)fminf(fmaxf(fy,      0.f), 65.f);
  const int qry = (int)fminf(fmaxf(fy + 1.f, 0.f), 65.f);
  const float wlx = 1.f + (float)qlx - pxc;
  const float wrx = 1.f - (float)qrx + pxc;
  const float wly = 1.f + (float)qly - pyc;
  const float wry = 1.f - (float)qry + pyc;
  const float glt = wlx*wly, grb = wrx*wry, glb = wlx*wry, grt = wrx*wly;

  const bool inxl = (qlx >= 1) && (qlx <= 64);
  const bool inxr = (qrx >= 1) && (qrx <= 64);
  const bool inyl = (qly >= 1) && (qly <= 64);
  const bool inyr = (qry >= 1) && (qry <= 64);

  const f32x4_t zero = (f32x4_t){0.f,0.f,0.f,0.f};
  #pragma unroll
  for (int b = 0; b < 2; ++b) {
    const float* xb = xT + (size_t)b * (64*64*256);
    f32x4_t vlt = (inxl && inyl) ? *(const f32x4_t*)&xb[((qlx-1)*64 + (qly-1))*256 + ic] : zero;
    f32x4_t vrb = (inxr && inyr) ? *(const f32x4_t*)&xb[((qrx-1)*64 + (qry-1))*256 + ic] : zero;
    f32x4_t vlb = (inxl && inyr) ? *(const f32x4_t*)&xb[((qlx-1)*64 + (qry-1))*256 + ic] : zero;
    f32x4_t vrt = (inxr && inyl) ? *(const f32x4_t*)&xb[((qrx-1)*64 + (qly-1))*256 + ic] : zero;
    ushort4 pk;
    float v0 = glt*vlt[0] + grb*vrb[0] + glb*vlb[0] + grt*vrt[0];
    float v1 = glt*vlt[1] + grb*vrb[1] + glb*vlb[1] + grt*vrt[1];
    float v2 = glt*vlt[2] + grb*vrb[2] + glb*vlb[2] + grt*vrt[2];
    float v3 = glt*vlt[3] + grb*vrb[3] + glb*vlb[3] + grt*vrt[3];
    pk.x = __hip_bfloat16_raw(__float2bfloat16(v0)).x;
    pk.y = __hip_bfloat16_raw(__float2bfloat16(v1)).x;
    pk.z = __hip_bfloat16_raw(__float2bfloat16(v2)).x;
    pk.w = __hip_bfloat16_raw(__float2bfloat16(v3)).x;
    *(ushort4*)&xoa[(((size_t)b*192 + i)*192 + j)*256 + ic] = pk;
  }
}

// implicit-GEMM conv: M=128 px (2 rows x 64 cols), N=128 oc, K=9 taps x 256 ic
// grid (6, 95, nZ): x = ntile(2) x coltile(3), y = row-pair, z = ab index
__global__ __launch_bounds__(256, 2) void k_conv(
    const __hip_bfloat16* __restrict__ xo,   // [z][192][192][256] bf16
    const __hip_bfloat16* __restrict__ wb,   // [9][256][256] bf16 (t,oc,ic)
    float* __restrict__ out)                 // + z*9241600 : [256][190][190]
{
  __shared__ __align__(16) char smem[66048];
  const int tid = threadIdx.x;
  const int nt = blockIdx.x & 1;
  const int ct = blockIdx.x >> 1;
  const int i0 = blockIdx.y * 2;
  const int z  = blockIdx.z;
  const int oc0 = nt * 128;
  const int j0 = ct * 64;

  const int q8   = tid >> 3;           // 0..31
  const int slot = tid & 7;
  const int wv   = tid >> 6;           // wave 0..3
  const int sw   = slot ^ (q8 & 7);    // XOR-swizzled 16B slot (pre-swizzle source)

  const char* xob = (const char*)xo + (size_t)z * 18874368u;
  const char* wbc = (const char*)wb;

  int arow[4], acol[4], brow[4];
  #pragma unroll
  for (int p = 0; p < 4; ++p) {
    const int m = p*32 + q8;
    arow[p] = i0 + (m >> 6);
    acol[p] = j0 + (m & 63);
    brow[p] = oc0 + m;
  }

  f32x4_t acc[4][4];
  #pragma unroll
  for (int fm = 0; fm < 4; ++fm)
    #pragma unroll
    for (int fn = 0; fn < 4; ++fn)
      acc[fm][fn] = (f32x4_t){0.f, 0.f, 0.f, 0.f};

  const int lane = tid & 63;
  const int lrow = lane & 15;
  const int lk   = lane >> 4;
  const int wm   = wv >> 1;
  const int wn   = wv & 1;

  auto stage = [&](int kk, int cur) {
    // TAP-INNER K order: tap = kk % 9, icg = kk / 9
    const int icg = kk / 9;
    const int t   = kk - icg*9;
    const int ki = t / 3, kj = t - 3*ki;
    char* sa = smem + cur*16384 + wv*1024;
    char* sb = smem + 32768 + cur*16384 + wv*1024;
    #pragma unroll
    for (int p = 0; p < 4; ++p) {
      int col = acol[p] + kj; col = (col > 191) ? 191 : col;   // garbage cols clamped (never stored)
      const char* ga = xob + (((arow[p] + ki)*192 + col)*256 + icg*64)*2 + sw*16;
      gload16(ga, sa + p*4096);
      const char* gb = wbc + ((t*256 + brow[p])*256 + icg*64)*2 + sw*16;
      gload16(gb, sb + p*4096);
    }
  };

  auto compute = [&](int cur) {
    const char* sa = smem + cur*16384;
    const char* sb = smem + 32768 + cur*16384;
    bf16x8_t af[4][2], bfr[4][2];
    #pragma unroll
    for (int f = 0; f < 4; ++f) {
      const int m = wm*64 + f*16 + lrow;
      const int n = wn*64 + f*16 + lrow;
      #pragma unroll
      for (int ks = 0; ks < 2; ++ks) {
        af[f][ks]  = *(const bf16x8_t*)(sa + m*128 + (((ks*4 + lk) ^ (m & 7)) * 16));
        bfr[f][ks] = *(const bf16x8_t*)(sb + n*128 + (((ks*4 + lk) ^ (n & 7)) * 16));
      }
    }
    #pragma unroll
    for (int fm = 0; fm < 4; ++fm)
      #pragma unroll
      for (int fn = 0; fn < 4; ++fn)
        #pragma unroll
        for (int ks = 0; ks < 2; ++ks)
          acc[fm][fn] = __builtin_amdgcn_mfma_f32_16x16x32_bf16(
              af[fm][ks], bfr[fn][ks], acc[fm][fn], 0, 0, 0);
  };

  stage(0, 0);
  __syncthreads();
  for (int kk = 0; kk < 36; ++kk) {
    const int cur = kk & 1;
    if (kk < 35) stage(kk + 1, cur ^ 1);
    compute(cur);
    __syncthreads();
  }

  // epilogue: LDS transpose to [oc'][m'] (pad 129) for coalesced NCHW stores
  float* eps = (float*)smem;
  #pragma unroll
  for (int fm = 0; fm < 4; ++fm)
    #pragma unroll
    for (int fn = 0; fn < 4; ++fn)
      #pragma unroll
      for (int r = 0; r < 4; ++r)
        eps[(wn*64 + fn*16 + lrow)*129 + (wm*64 + fm*16 + lk*4 + r)] = acc[fm][fn][r];
  __syncthreads();

  float* outb = out + (size_t)z * 9241600u;
  #pragma unroll
  for (int pass = 0; pass < 16; ++pass) {
    const int ocw = pass*8 + (tid >> 5);
    const int m4  = (tid & 31) * 4;
    const int di  = m4 >> 6, jc = m4 & 63;
    const int i = i0 + di, j = j0 + jc;
    const float v0 = eps[ocw*129 + m4 + 0];
    const float v1 = eps[ocw*129 + m4 + 1];
    const float v2 = eps[ocw*129 + m4 + 2];
    const float v3 = eps[ocw*129 + m4 + 3];
    float* dst = outb + ((size_t)(oc0 + ocw)*190 + i)*190 + j;
    if (j + 3 < 190) {
      *(float2*)dst       = make_float2(v0, v1);   // 8B-aligned always
      *(float2*)(dst + 2) = make_float2(v2, v3);
    } else {
      if (j     < 190) dst[0] = v0;
      if (j + 1 < 190) dst[1] = v1;
      if (j + 2 < 190) dst[2] = v2;
      if (j + 3 < 190) dst[3] = v3;
    }
  }
}

extern "C" void kernel_launch(void* const* d_in, const int* in_sizes, int n_in,
                              void* d_out, int out_size, void* d_ws, size_t ws_size,
                              hipStream_t stream)
{
  const float* x = (const float*)d_in[0];
  const float* w = (const float*)d_in[1];
  float* out = (float*)d_out;

  char* ws = (char*)d_ws;
  float*          xT = (float*)ws;                         // 8,388,608 B
  __hip_bfloat16* wb = (__hip_bfloat16*)(ws + 8388608);    // 1,179,648 B
  __hip_bfloat16* xo = (__hip_bfloat16*)(ws + 9568256);    // 5 or 1 x 37,748,736 B

  const bool merged = (ws_size >= 198311936ull);

  k_transpose<<<dim3(64, 64, 2), 256, 0, stream>>>(x, xT);
  k_wconv<<<2304, 256, 0, stream>>>(w, wb);

  if (merged) {
    k_sample<<<dim3(48, 192, 5), 256, 0, stream>>>(xT, xo, 0);
    k_conv<<<dim3(6, 95, 10), 256, 0, stream>>>(xo, wb, out);
  } else {
    for (int aidx = 0; aidx < 5; ++aidx) {
      k_sample<<<dim3(48, 192, 1), 256, 0, stream>>>(xT, xo, aidx);
      k_conv<<<dim3(6, 95, 2), 256, 0, stream>>>(xo, wb, out + (size_t)aidx * 18483200u);
    }
  }
}